// Round 1
// 202.252 us; speedup vs baseline: 1.0142x; 1.0142x over previous
//
#include <hip/hip_runtime.h>
#include <hip/hip_bf16.h>
#include <math.h>

#define BB 2
#define CC 1024
#define TT 2048
#define HH 16
#define DD 64

using short8   = __attribute__((ext_vector_type(8))) short;
using floatx4  = __attribute__((ext_vector_type(4))) float;
using floatx16 = __attribute__((ext_vector_type(16))) float;
typedef unsigned short ushort_t;

#define MFMA(a, b, c) __builtin_amdgcn_mfma_f32_16x16x32_bf16((a), (b), (c), 0, 0, 0)
#define MFMA32(a, b, c) __builtin_amdgcn_mfma_f32_32x32x16_bf16((a), (b), (c), 0, 0, 0)

// Q pre-scale: SCALE * log2(e) so attn softmax runs in exp2 domain.
#define QSC 0.18033688011112042f

// bf16-domain Schraudolph: f = fma(s,128,PMAGIC) with f in [2^23,2^24) means
// low16(bits(f)) == round(s*128 + 16249) == bf16 encoding of ~2^s.
// 16249 = 127*2^7 - round(486400/2^16)  (classic Schraudolph bias, rescaled).
// At s==0 this yields bf16 0x3F79 = 0.97265625 exactly (PZERO_BF).
#define PMAGIC   8404857.0f   /* 2^23 + 16249 */
#define PZERO_BF 0.97265625f

__device__ __forceinline__ ushort_t f2bf(float f) {          // RNE (O-path)
    unsigned int u = __float_as_uint(f);
    u += 0x7FFFu + ((u >> 16) & 1u);
    return (ushort_t)(u >> 16);
}
__device__ __forceinline__ float bf2f(ushort_t h) {
    return __uint_as_float(((unsigned int)h) << 16);
}
__device__ __forceinline__ ushort_t f2bf_t(float f) {        // truncation
    return (ushort_t)(__float_as_uint(f) >> 16);
}
// single v_perm_b32: pack high halves of two floats (truncation to bf16)
__device__ __forceinline__ unsigned int packtrunc(float a, float b) {
    return __builtin_amdgcn_perm(__float_as_uint(b), __float_as_uint(a),
                                 0x07060302u);
}
// bf16-domain Schraudolph exp2 of two scores -> packed bf16x2.
// 1 v_fma_f32 per element + 1 v_perm per pair (vs fma+cvt+perm before).
__device__ __forceinline__ unsigned int pack2bf_exp(float s0, float s1) {
    float f0 = fmaf(s0, 128.0f, PMAGIC);
    float f1 = fmaf(s1, 128.0f, PMAGIC);
    // low16 of each holds the bf16; pack (f0.lo16, f1.lo16)
    return __builtin_amdgcn_perm(__float_as_uint(f1), __float_as_uint(f0),
                                 0x05040100u);
}
// async global->LDS, 16B per lane, dest = uniform base + lane*16
__device__ __forceinline__ void load_lds16(const void* g, void* s) {
    __builtin_amdgcn_global_load_lds(
        (const __attribute__((address_space(1))) void*)g,
        (__attribute__((address_space(3))) void*)s, 16, 0, 0);
}

// ---- workspace byte offsets (bf16 arena starts at 64KB) --------------------
static constexpr size_t B0       = 65536;
static constexpr size_t XT_OFF   = B0;                       // [B][T][C] bf16; later reused for OT
static constexpr size_t WQKV_OFF = XT_OFF   + 8388608;       // [3072][1024]
static constexpr size_t WP_OFF   = WQKV_OFF + 6291456;       // [1024][1024]
static constexpr size_t Q_OFF    = WP_OFF   + 2097152;       // [B][H][T][D]
static constexpr size_t K_OFF    = Q_OFF    + 8388608;
static constexpr size_t V_OFF    = K_OFF    + 8388608;       // [B][C][T]
static constexpr size_t OP_OFF   = V_OFF    + 8388608;       // Opart[2][B][T][C] bf16
static constexpr size_t ML_OFF   = OP_OFF   + 16777216;      // l[2][B][H][T] fp32

// ---------------------------------------------------------------------------
// Merged prep kernel:
//   blocks [0,4096)      : weight conversion (WQKV, WP)
//   blocks [4096,5120)   : x transpose -> XT bf16
//   blocks [5120,5136)   : mask expand (self-detecting dtype) + nmcnt
// ---------------------------------------------------------------------------
__global__ __launch_bounds__(256) void prep_kernel(
    const float* __restrict__ x, const float* __restrict__ Wq,
    const float* __restrict__ Wk, const float* __restrict__ Wv,
    const float* __restrict__ Wp, const unsigned int* __restrict__ mraw,
    ushort_t* __restrict__ XT, ushort_t* __restrict__ WQKV,
    ushort_t* __restrict__ WP, float* __restrict__ maskf,
    int* __restrict__ nmcnt, float* __restrict__ out_tail) {
    __shared__ float tile[64][65];
    const int bid = blockIdx.x;
    const int tid = threadIdx.x;
    if (bid < 4096) {
        const int idx = bid * 256 + tid;  // quad index
        if (idx < 786432) {
            int row = idx >> 8;
            int qc  = idx & 255;
            const float* src = row < 1024 ? Wq : (row < 2048 ? Wk : Wv);
            float4 v = *(const float4*)&src[(size_t)(row & 1023) * CC + qc * 4];
            ushort4 pk; pk.x = f2bf(v.x); pk.y = f2bf(v.y);
            pk.z = f2bf(v.z); pk.w = f2bf(v.w);
            *(ushort4*)&WQKV[(size_t)idx * 4] = pk;
        } else {
            int j = idx - 786432;
            float4 v = *(const float4*)&Wp[(size_t)j * 4];
            ushort4 pk; pk.x = f2bf(v.x); pk.y = f2bf(v.y);
            pk.z = f2bf(v.z); pk.w = f2bf(v.w);
            *(ushort4*)&WP[(size_t)j * 4] = pk;
        }
    } else if (bid < 5120) {
        const int xb = bid - 4096;
        const int t0 = (xb & 31) * 64, c0 = ((xb >> 5) & 15) * 64, b = xb >> 9;
        const int tc = tid & 15, tr = tid >> 4;
        #pragma unroll
        for (int p = 0; p < 4; p++) {
            int cl = tr + p * 16;
            float4 v = *(const float4*)&x[((size_t)b * CC + c0 + cl) * TT + t0 + tc * 4];
            tile[cl][tc * 4 + 0] = v.x; tile[cl][tc * 4 + 1] = v.y;
            tile[cl][tc * 4 + 2] = v.z; tile[cl][tc * 4 + 3] = v.w;
        }
        __syncthreads();
        #pragma unroll
        for (int p = 0; p < 4; p++) {
            int tl = tr + p * 16;
            ushort4 pk;
            pk.x = f2bf(tile[tc * 4 + 0][tl]);
            pk.y = f2bf(tile[tc * 4 + 1][tl]);
            pk.z = f2bf(tile[tc * 4 + 2][tl]);
            pk.w = f2bf(tile[tc * 4 + 3][tl]);
            *(ushort4*)&XT[((size_t)b * TT + t0 + tl) * CC + c0 + tc * 4] = pk;
        }
    } else {
        __shared__ int ev_bf16, ev_bool, cnt;
        const int mb = bid - 5120;      // 0..15
        if (tid == 0) { ev_bf16 = 0; ev_bool = 0; cnt = 0; }
        __syncthreads();
        for (int i = tid; i < 1024; i += 256) {
            unsigned int w = mraw[i];
            if ((w & 0xFFFFu) == 0x3F80u) atomicOr(&ev_bf16, 1);
            if ((w & 0xFFFFFF00u) != 0u && w != 0x3F800000u) atomicOr(&ev_bool, 1);
        }
        __syncthreads();
        const int mode = ev_bf16 ? 2 : (ev_bool ? 1 : 0);
        const int e = mb * 256 + tid;
        bool on;
        if (mode == 2)      on = ((const ushort_t*)mraw)[e] != 0;
        else if (mode == 1) on = ((const unsigned char*)mraw)[e] != 0;
        else                on = mraw[e] != 0;
        maskf[e]    = on ? 1.0f : 0.0f;
        out_tail[e] = on ? 1.0f : 0.0f;
        if (!on) atomicAdd(&cnt, 1);
        __syncthreads();
        if (tid == 0) nmcnt[mb] = cnt;
    }
}

// ---------------------------------------------------------------------------
// Fused QKV GEMM (proven R11). q pre-scaled by QSC; K,V masked columns zeroed.
// ---------------------------------------------------------------------------
__global__ __launch_bounds__(256) void gemm_qkv_kernel(
    const ushort_t* __restrict__ Wqkv, const float* __restrict__ bq,
    const float* __restrict__ bk, const float* __restrict__ bv,
    const ushort_t* __restrict__ XT, const float* __restrict__ maskf,
    ushort_t* __restrict__ Qo, ushort_t* __restrict__ Ko,
    ushort_t* __restrict__ Vo) {
    __shared__ ushort_t As[128][32];
    __shared__ ushort_t Bs[128][32];
    __shared__ float biasS[128];

    const int b = blockIdx.z;
    const int m0 = blockIdx.y * 128;
    const int n0 = blockIdx.x * 128;
    const int tid = threadIdx.x;
    const int lane = tid & 63;
    const int w = tid >> 6;
    const int wm = (w & 1) * 64, wn = (w >> 1) * 64;
    const int la = lane & 15, lg = lane >> 4;
    const int region = m0 >> 10;  // 0=q 1=k 2=v

    const float* bsrc = region == 0 ? (bq + m0)
                      : (region == 1 ? (bk + m0 - 1024) : (bv + m0 - 2048));
    if (tid < 128) biasS[tid] = bsrc[tid];

    // per-column scale, loaded up-front: Q -> QSC; K,V -> mask
    float csc[4];
    #pragma unroll
    for (int nt = 0; nt < 4; nt++) {
        const int t = n0 + wn + nt * 16 + la;
        csc[nt] = (region == 0) ? QSC : maskf[b * TT + t];
    }

    floatx4 zero4 = {0.f, 0.f, 0.f, 0.f};
    floatx4 acc[4][4];
    #pragma unroll
    for (int mt = 0; mt < 4; mt++)
        #pragma unroll
        for (int nt = 0; nt < 4; nt++) acc[mt][nt] = zero4;

    const ushort_t* Abase = Wqkv + (size_t)m0 * CC;
    const ushort_t* Bbase = XT + ((size_t)b * TT + n0) * CC;
    const int rl = lane >> 2;
    const int cl = (lane & 3) * 8;

    for (int k0 = 0; k0 < CC; k0 += 32) {
        #pragma unroll
        for (int c = 0; c < 2; c++) {
            int row = w * 32 + c * 16;
            load_lds16(Abase + (size_t)(row + rl) * CC + k0 + cl, &As[row][0]);
            load_lds16(Bbase + (size_t)(row + rl) * CC + k0 + cl, &Bs[row][0]);
        }
        __syncthreads();
        short8 af[4], bf[4];
        #pragma unroll
        for (int mt = 0; mt < 4; mt++)
            af[mt] = *(const short8*)&As[wm + mt * 16 + la][lg * 8];
        #pragma unroll
        for (int nt = 0; nt < 4; nt++)
            bf[nt] = *(const short8*)&Bs[wn + nt * 16 + la][lg * 8];
        #pragma unroll
        for (int mt = 0; mt < 4; mt++)
            #pragma unroll
            for (int nt = 0; nt < 4; nt++)
                acc[mt][nt] = MFMA(af[mt], bf[nt], acc[mt][nt]);
        __syncthreads();
    }

    #pragma unroll
    for (int mt = 0; mt < 4; mt++) {
        const int lm = wm + mt * 16 + lg * 4;
        const int gm = m0 + lm;
        #pragma unroll
        for (int nt = 0; nt < 4; nt++) {
            const int t = n0 + wn + nt * 16 + la;
            const float sc = csc[nt];
            float v0 = (acc[mt][nt][0] + biasS[lm + 0]) * sc;
            float v1 = (acc[mt][nt][1] + biasS[lm + 1]) * sc;
            float v2 = (acc[mt][nt][2] + biasS[lm + 2]) * sc;
            float v3 = (acc[mt][nt][3] + biasS[lm + 3]) * sc;
            if (region < 2) {
                int mq = gm & 1023;
                int hh = mq >> 6, db = mq & 63;
                ushort_t* dst = (region == 0 ? Qo : Ko)
                              + (((size_t)b * HH + hh) * TT + t) * DD + db;
                uint2 pk;
                pk.x = packtrunc(v0, v1);
                pk.y = packtrunc(v2, v3);
                *(uint2*)dst = pk;
            } else {
                int c = gm & 1023;
                Vo[((size_t)b * CC + c + 0) * TT + t] = f2bf_t(v0);
                Vo[((size_t)b * CC + c + 1) * TT + t] = f2bf_t(v1);
                Vo[((size_t)b * CC + c + 2) * TT + t] = f2bf_t(v2);
                Vo[((size_t)b * CC + c + 3) * TT + t] = f2bf_t(v3);
            }
        }
    }
}

// ---------------------------------------------------------------------------
// Flash attention v9: VALU-diet softmax.
//   - bf16-domain Schraudolph: one v_fma_f32 per score yields the bf16
//     probability directly in low16 bits (no v_cvt_i32_f32 per element).
//   - row-sum l via one extra MFMA32(ones, pf) per kc: replaces 32 VALU adds
//     per tile AND the final half-wave shuffle; denominator now sums the
//     exact bf16 p values the PV numerator uses.
// ---------------------------------------------------------------------------
__global__ __launch_bounds__(256) void attn_kernel(
    const ushort_t* __restrict__ Qg, const ushort_t* __restrict__ Kg,
    const ushort_t* __restrict__ Vg, const int* __restrict__ nmcnt,
    ushort_t* __restrict__ Opart, float* __restrict__ lbuf) {
    __shared__ ushort_t Ks[2][64][72];   // [buf][key][d]
    __shared__ ushort_t Vs[2][64][72];   // [buf][d][key]

    const int sp = blockIdx.z & 1, b = blockIdx.z >> 1;
    const int hh = blockIdx.y, t0 = blockIdx.x * 128;
    const int j0base = sp * (TT / 2);
    const int tid  = threadIdx.x;
    const int lane = tid & 63;
    const int w    = tid >> 6;
    const int ln31 = lane & 31;
    const int h    = lane >> 5;
    const size_t qkbase = ((size_t)b * HH + hh) * TT * DD;
    const size_t vbase  = ((size_t)b * CC + hh * DD) * TT;

    const int tq = t0 + w * 32 + ln31;
    short8 qreg[4];
    {
        const ushort_t* qp = Qg + qkbase + (size_t)tq * DD + h * 8;
        #pragma unroll
        for (int kc = 0; kc < 4; kc++)
            qreg[kc] = *(const short8*)(qp + kc * 16);
    }

    const int srow = tid >> 2;
    const int scol = (tid & 3) * 16;
    const ushort_t* kbase = Kg + qkbase + (size_t)srow * DD + scol;
    const ushort_t* vbptr = Vg + vbase + (size_t)srow * TT + scol;

    // prologue: issue loads for tile 0
    int4 kpre0, kpre1, vpre0, vpre1;
    {
        const ushort_t* kp = kbase + (size_t)j0base * DD;
        const ushort_t* vp = vbptr + j0base;
        kpre0 = *(const int4*)(kp);  kpre1 = *(const int4*)(kp + 8);
        vpre0 = *(const int4*)(vp);  vpre1 = *(const int4*)(vp + 8);
    }

    floatx16 zero16 = {0.f,0.f,0.f,0.f,0.f,0.f,0.f,0.f,
                       0.f,0.f,0.f,0.f,0.f,0.f,0.f,0.f};
    floatx16 oacc[2];
    oacc[0] = zero16; oacc[1] = zero16;
    floatx16 lacc = zero16;              // every reg = sum_k p[k][q]
    short8 ones8;
    #pragma unroll
    for (int i = 0; i < 8; i++) ones8[i] = (short)0x3F80;   // bf16 1.0

    for (int kt = 0; kt < 16; kt++) {
        const int p = kt & 1;
        // store tile kt (waits on its loads — which had a full tile to land)
        *(int4*)&Ks[p][srow][scol]     = kpre0;
        *(int4*)&Ks[p][srow][scol + 8] = kpre1;
        *(int4*)&Vs[p][srow][scol]     = vpre0;
        *(int4*)&Vs[p][srow][scol + 8] = vpre1;
        __syncthreads();
        // issue loads for tile kt+1 AFTER the barrier: in flight during compute
        if (kt < 15) {
            const int j0n = j0base + (kt + 1) * 64;
            const ushort_t* kp = kbase + (size_t)j0n * DD;
            const ushort_t* vp = vbptr + j0n;
            kpre0 = *(const int4*)(kp);  kpre1 = *(const int4*)(kp + 8);
            vpre0 = *(const int4*)(vp);  vpre1 = *(const int4*)(vp + 8);
        }

        // ---- S^T = K · Q^T ----
        floatx16 sacc[2];
        sacc[0] = zero16; sacc[1] = zero16;
        #pragma unroll
        for (int kc = 0; kc < 4; kc++) {
            #pragma unroll
            for (int mt = 0; mt < 2; mt++) {
                short8 kf = *(const short8*)&Ks[p][mt * 32 + ln31][kc * 16 + h * 8];
                sacc[mt] = MFMA32(kf, qreg[kc], sacc[mt]);
            }
        }

        // ---- bf16-domain Schraudolph: p_bf16 = low16(fma(s,128,PMAGIC)) ----
        unsigned int pd[16];
        #pragma unroll
        for (int mt = 0; mt < 2; mt++)
            #pragma unroll
            for (int g = 0; g < 4; g++) {
                pd[mt * 8 + g * 2 + 0] =
                    pack2bf_exp(sacc[mt][g * 4 + 0], sacc[mt][g * 4 + 1]);
                pd[mt * 8 + g * 2 + 1] =
                    pack2bf_exp(sacc[mt][g * 4 + 2], sacc[mt][g * 4 + 3]);
            }

        // ---- PV: B-frag via half-wave exchange; l-sum via ones-MFMA ----
        #pragma unroll
        for (int kc = 0; kc < 4; kc++) {
            const int base = (kc >> 1) * 8 + (kc & 1) * 4;
            int a0 = pd[base], a1 = pd[base + 1], a2 = pd[base + 2], a3 = pd[base + 3];
            int x0 = __shfl_xor(h ? a0 : a2, 32, 64);
            int x1 = __shfl_xor(h ? a1 : a3, 32, 64);
            int4 fi;
            fi.x = h ? x0 : a0;
            fi.y = h ? x1 : a1;
            fi.z = h ? a2 : x0;
            fi.w = h ? a3 : x1;
            short8 pf = *(short8*)&fi;
            lacc = MFMA32(ones8, pf, lacc);   // all rows = sum over k (both halves)
            #pragma unroll
            for (int dt = 0; dt < 2; dt++) {
                short8 vf = *(const short8*)&Vs[p][dt * 32 + ln31][kc * 16 + h * 8];
                oacc[dt] = MFMA32(vf, pf, oacc[dt]);
            }
        }
    }

    // lacc[0] holds the full split-sum over all 1024 keys (K-reduction spans
    // both half-waves — no shuffle needed). Remove masked keys' exact
    // bf16(approx 2^0) = 0.97265625 contributions (exact in fp32: n*249/256).
    float lsum = lacc[0];
    {
        const int r4 = (b * 2 + sp) * 4;
        int nm = nmcnt[r4] + nmcnt[r4 + 1] + nmcnt[r4 + 2] + nmcnt[r4 + 3];
        lsum -= (float)nm * PZERO_BF;
    }

    // ---- epilogue: Opart = O_s/l_s (bf16 RNE — O-path stays unbiased) ----
    const float inv = lsum > 0.0f ? 1.0f / lsum : 0.0f;
    ushort_t* OP = Opart + (size_t)sp * ((size_t)BB * TT * CC)
                 + ((size_t)b * TT + tq) * CC + hh * 64;
    #pragma unroll
    for (int mt = 0; mt < 2; mt++)
        #pragma unroll
        for (int g = 0; g < 4; g++) {
            int db = mt * 32 + g * 8 + h * 4;
            ushort4 pk;
            pk.x = f2bf(oacc[mt][g * 4 + 0] * inv);
            pk.y = f2bf(oacc[mt][g * 4 + 1] * inv);
            pk.z = f2bf(oacc[mt][g * 4 + 2] * inv);
            pk.w = f2bf(oacc[mt][g * 4 + 3] * inv);
            *(ushort4*)&OP[db] = pk;
        }
    if (h == 0)
        lbuf[(((size_t)sp * BB + b) * HH + hh) * TT + tq] = lsum;
}

// ---------------------------------------------------------------------------
// Combine splits: OT = w0*P0 + w1*P1, w_s = l_s/(l0+l1).
// ---------------------------------------------------------------------------
__global__ __launch_bounds__(256) void combine_kernel(
    const ushort_t* __restrict__ Opart, const float* __restrict__ lbuf,
    ushort_t* __restrict__ OT) {
    const size_t idx = ((size_t)blockIdx.x * 256 + threadIdx.x) * 8;
    const int c0 = (int)(idx & (CC - 1));
    const int t  = (int)((idx >> 10) & (TT - 1));
    const int b  = (int)(idx >> 21);
    const int hh = c0 >> 6;
    const float l0 = lbuf[(((size_t)0 * BB + b) * HH + hh) * TT + t];
    const float l1 = lbuf[(((size_t)1 * BB + b) * HH + hh) * TT + t];
    const float sum = l0 + l1;
    const float ws = sum > 0.0f ? 1.0f / sum : 0.0f;
    const float w0 = l0 * ws, w1 = l1 * ws;
    const ushort_t* P0 = Opart + idx;
    const ushort_t* P1 = Opart + (size_t)BB * TT * CC + idx;
    ushort4 a0 = *(const ushort4*)(P0);
    ushort4 a1 = *(const ushort4*)(P0 + 4);
    ushort4 b0 = *(const ushort4*)(P1);
    ushort4 b1 = *(const ushort4*)(P1 + 4);
    ushort4 o0, o1;
    o0.x = f2bf(w0 * bf2f(a0.x) + w1 * bf2f(b0.x));
    o0.y = f2bf(w0 * bf2f(a0.y) + w1 * bf2f(b0.y));
    o0.z = f2bf(w0 * bf2f(a0.z) + w1 * bf2f(b0.z));
    o0.w = f2bf(w0 * bf2f(a0.w) + w1 * bf2f(b0.w));
    o1.x = f2bf(w0 * bf2f(a1.x) + w1 * bf2f(b1.x));
    o1.y = f2bf(w0 * bf2f(a1.y) + w1 * bf2f(b1.y));
    o1.z = f2bf(w0 * bf2f(a1.z) + w1 * bf2f(b1.z));
    o1.w = f2bf(w0 * bf2f(a1.w) + w1 * bf2f(b1.w));
    *(ushort4*)&OT[idx]     = o0;
    *(ushort4*)&OT[idx + 4] = o1;
}

// ---------------------------------------------------------------------------
// Output GEMM, single-pass bf16 (proven R7/R8).
// ---------------------------------------------------------------------------
__global__ __launch_bounds__(256) void gemm_out_kernel(
    const ushort_t* __restrict__ WP, const ushort_t* __restrict__ OT,
    const float* __restrict__ bp, const float* __restrict__ maskf,
    float* __restrict__ out) {
    __shared__ ushort_t As[64][32];
    __shared__ ushort_t Bs[128][32];
    __shared__ float biasS[64];

    const int b = blockIdx.z;
    const int m0 = blockIdx.y * 64;
    const int n0 = blockIdx.x * 128;
    const int tid = threadIdx.x;
    const int lane = tid & 63;
    const int w = tid >> 6;
    const int wm = (w & 1) * 32, wn = (w >> 1) * 64;
    const int la = lane & 15, lg = lane >> 4;

    if (tid < 64) biasS[tid] = bp[m0 + tid];

    floatx4 zero4 = {0.f, 0.f, 0.f, 0.f};
    floatx4 acc[2][4];
    #pragma unroll
    for (int mt = 0; mt < 2; mt++)
        #pragma unroll
        for (int nt = 0; nt < 4; nt++) acc[mt][nt] = zero4;

    const int rl = lane >> 2;
    const int cl = (lane & 3) * 8;
    const ushort_t* Bbase = OT + ((size_t)b * TT + n0) * CC;

    for (int k0 = 0; k0 < CC; k0 += 32) {
        {
            int row = w * 16;
            load_lds16(WP + (size_t)(m0 + row + rl) * CC + k0 + cl, &As[row][0]);
        }
        #pragma unroll
        for (int c = 0; c < 2; c++) {
            int row = w * 32 + c * 16;
            load_lds16(Bbase + (size_t)(row + rl) * CC + k0 + cl, &Bs[row][0]);
        }
        __syncthreads();
        short8 af[2], bf[4];
        #pragma unroll
        for (int mt = 0; mt < 2; mt++)
            af[mt] = *(const short8*)&As[wm + mt * 16 + la][lg * 8];
        #pragma unroll
        for (int nt = 0; nt < 4; nt++)
            bf[nt] = *(const short8*)&Bs[wn + nt * 16 + la][lg * 8];
        #pragma unroll
        for (int mt = 0; mt < 2; mt++)
            #pragma unroll
            for (int nt = 0; nt < 4; nt++)
                acc[mt][nt] = MFMA(af[mt], bf[nt], acc[mt][nt]);
        __syncthreads();
    }

    #pragma unroll
    for (int mt = 0; mt < 2; mt++) {
        const int lm = wm + mt * 16 + lg * 4;
        #pragma unroll
        for (int nt = 0; nt < 4; nt++) {
            const int t = n0 + wn + nt * 16 + la;
            const float mk = maskf[b * TT + t];
            #pragma unroll
            for (int r = 0; r < 4; r++)
                out[((size_t)b * CC + m0 + lm + r) * TT + t] =
                    (acc[mt][nt][r] + biasS[lm + r]) * mk;
        }
    }
}

// ---------------------------------------------------------------------------
extern "C" void kernel_launch(void* const* d_in, const int* in_sizes, int n_in,
                              void* d_out, int out_size, void* d_ws,
                              size_t ws_size, hipStream_t stream) {
    const float* x    = (const float*)d_in[0];
    const void*  mask = d_in[1];
    const float* Wq   = (const float*)d_in[2];
    const float* bq   = (const float*)d_in[3];
    const float* Wk   = (const float*)d_in[4];
    const float* bk   = (const float*)d_in[5];
    const float* Wv   = (const float*)d_in[6];
    const float* bv   = (const float*)d_in[7];
    const float* Wp   = (const float*)d_in[8];
    const float* bp   = (const float*)d_in[9];

    float* out  = (float*)d_out;
    float* wsf  = (float*)d_ws;
    int* nmcnt  = (int*)d_ws + 16;     // 16 per-block masked counts
    float* maskf = wsf + 1024;
    char* wsb = (char*)d_ws;
    ushort_t* XT    = (ushort_t*)(wsb + XT_OFF);   // also final OT
    ushort_t* WQKV  = (ushort_t*)(wsb + WQKV_OFF);
    ushort_t* WPb   = (ushort_t*)(wsb + WP_OFF);
    ushort_t* Qb    = (ushort_t*)(wsb + Q_OFF);
    ushort_t* Kb    = (ushort_t*)(wsb + K_OFF);
    ushort_t* Vb    = (ushort_t*)(wsb + V_OFF);
    ushort_t* Opart = (ushort_t*)(wsb + OP_OFF);
    float*    lbuf  = (float*)(wsb + ML_OFF);

    prep_kernel<<<5136, 256, 0, stream>>>(x, Wq, Wk, Wv, Wp,
                                          (const unsigned int*)mask, XT, WQKV,
                                          WPb, maskf, nmcnt,
                                          out + (size_t)BB * CC * TT);

    gemm_qkv_kernel<<<dim3(TT / 128, 3 * CC / 128, BB), 256, 0, stream>>>(
        WQKV, bq, bk, bv, XT, maskf, Qb, Kb, Vb);

    attn_kernel<<<dim3(TT / 128, HH, BB * 2), 256, 0, stream>>>(
        Qb, Kb, Vb, nmcnt, Opart, lbuf);

    combine_kernel<<<2048, 256, 0, stream>>>(Opart, lbuf, XT);

    gemm_out_kernel<<<dim3(TT / 128, CC / 64, BB), 256, 0, stream>>>(
        WPb, XT, bp, maskf, out);
}

// Round 2
// 192.615 us; speedup vs baseline: 1.0649x; 1.0500x over previous
//
#include <hip/hip_runtime.h>
#include <hip/hip_bf16.h>
#include <math.h>

#define BB 2
#define CC 1024
#define TT 2048
#define HH 16
#define DD 64

using short8   = __attribute__((ext_vector_type(8))) short;
using floatx4  = __attribute__((ext_vector_type(4))) float;
using floatx16 = __attribute__((ext_vector_type(16))) float;
using uint2v   = __attribute__((ext_vector_type(2))) unsigned int;
typedef unsigned short ushort_t;

#define MFMA(a, b, c) __builtin_amdgcn_mfma_f32_16x16x32_bf16((a), (b), (c), 0, 0, 0)
#define MFMA32(a, b, c) __builtin_amdgcn_mfma_f32_32x32x16_bf16((a), (b), (c), 0, 0, 0)

// Q pre-scale: SCALE * log2(e) so attn softmax runs in exp2 domain.
#define QSC 0.18033688011112042f

// bf16-domain Schraudolph: f = fma(s,128,PMAGIC) with f in [2^23,2^24) means
// low16(bits(f)) == round(s*128 + 16249) == bf16 encoding of ~2^s.
// At s==0 this yields bf16 0x3F79 = 0.97265625 exactly (PZERO_BF).
#define PMAGIC   8404857.0f   /* 2^23 + 16249 */
#define PZERO_BF 0.97265625f

__device__ __forceinline__ ushort_t f2bf(float f) {          // RNE (O-path)
    unsigned int u = __float_as_uint(f);
    u += 0x7FFFu + ((u >> 16) & 1u);
    return (ushort_t)(u >> 16);
}
__device__ __forceinline__ float bf2f(ushort_t h) {
    return __uint_as_float(((unsigned int)h) << 16);
}
__device__ __forceinline__ ushort_t f2bf_t(float f) {        // truncation
    return (ushort_t)(__float_as_uint(f) >> 16);
}
// single v_perm_b32: pack high halves of two floats (truncation to bf16)
__device__ __forceinline__ unsigned int packtrunc(float a, float b) {
    return __builtin_amdgcn_perm(__float_as_uint(b), __float_as_uint(a),
                                 0x07060302u);
}
// bf16-domain Schraudolph exp2 of two scores -> packed bf16x2.
__device__ __forceinline__ unsigned int pack2bf_exp(float s0, float s1) {
    float f0 = fmaf(s0, 128.0f, PMAGIC);
    float f1 = fmaf(s1, 128.0f, PMAGIC);
    return __builtin_amdgcn_perm(__float_as_uint(f1), __float_as_uint(f0),
                                 0x05040100u);
}
// async global->LDS, 16B per lane, dest = uniform base + lane*16
__device__ __forceinline__ void load_lds16(const void* g, void* s) {
    __builtin_amdgcn_global_load_lds(
        (const __attribute__((address_space(1))) void*)g,
        (__attribute__((address_space(3))) void*)s, 16, 0, 0);
}

// ---- workspace byte offsets (bf16 arena starts at 64KB) --------------------
static constexpr size_t B0       = 65536;
static constexpr size_t XT_OFF   = B0;                       // [B][T][C] bf16; later reused for OT
static constexpr size_t WQKV_OFF = XT_OFF   + 8388608;       // [3072][1024]
static constexpr size_t WP_OFF   = WQKV_OFF + 6291456;       // [1024][1024]
static constexpr size_t Q_OFF    = WP_OFF   + 2097152;       // [B][H][T][D]
static constexpr size_t K_OFF    = Q_OFF    + 8388608;
static constexpr size_t V_OFF    = K_OFF    + 8388608;       // [B][C][T]
static constexpr size_t OP_OFF   = V_OFF    + 8388608;       // Opart[2][B][T][C] bf16
static constexpr size_t ML_OFF   = OP_OFF   + 16777216;      // l[2][B][H][T] fp32

// ---------------------------------------------------------------------------
// Merged prep kernel (unchanged).
// ---------------------------------------------------------------------------
__global__ __launch_bounds__(256) void prep_kernel(
    const float* __restrict__ x, const float* __restrict__ Wq,
    const float* __restrict__ Wk, const float* __restrict__ Wv,
    const float* __restrict__ Wp, const unsigned int* __restrict__ mraw,
    ushort_t* __restrict__ XT, ushort_t* __restrict__ WQKV,
    ushort_t* __restrict__ WP, float* __restrict__ maskf,
    int* __restrict__ nmcnt, float* __restrict__ out_tail) {
    __shared__ float tile[64][65];
    const int bid = blockIdx.x;
    const int tid = threadIdx.x;
    if (bid < 4096) {
        const int idx = bid * 256 + tid;  // quad index
        if (idx < 786432) {
            int row = idx >> 8;
            int qc  = idx & 255;
            const float* src = row < 1024 ? Wq : (row < 2048 ? Wk : Wv);
            float4 v = *(const float4*)&src[(size_t)(row & 1023) * CC + qc * 4];
            ushort4 pk; pk.x = f2bf(v.x); pk.y = f2bf(v.y);
            pk.z = f2bf(v.z); pk.w = f2bf(v.w);
            *(ushort4*)&WQKV[(size_t)idx * 4] = pk;
        } else {
            int j = idx - 786432;
            float4 v = *(const float4*)&Wp[(size_t)j * 4];
            ushort4 pk; pk.x = f2bf(v.x); pk.y = f2bf(v.y);
            pk.z = f2bf(v.z); pk.w = f2bf(v.w);
            *(ushort4*)&WP[(size_t)j * 4] = pk;
        }
    } else if (bid < 5120) {
        const int xb = bid - 4096;
        const int t0 = (xb & 31) * 64, c0 = ((xb >> 5) & 15) * 64, b = xb >> 9;
        const int tc = tid & 15, tr = tid >> 4;
        #pragma unroll
        for (int p = 0; p < 4; p++) {
            int cl = tr + p * 16;
            float4 v = *(const float4*)&x[((size_t)b * CC + c0 + cl) * TT + t0 + tc * 4];
            tile[cl][tc * 4 + 0] = v.x; tile[cl][tc * 4 + 1] = v.y;
            tile[cl][tc * 4 + 2] = v.z; tile[cl][tc * 4 + 3] = v.w;
        }
        __syncthreads();
        #pragma unroll
        for (int p = 0; p < 4; p++) {
            int tl = tr + p * 16;
            ushort4 pk;
            pk.x = f2bf(tile[tc * 4 + 0][tl]);
            pk.y = f2bf(tile[tc * 4 + 1][tl]);
            pk.z = f2bf(tile[tc * 4 + 2][tl]);
            pk.w = f2bf(tile[tc * 4 + 3][tl]);
            *(ushort4*)&XT[((size_t)b * TT + t0 + tl) * CC + c0 + tc * 4] = pk;
        }
    } else {
        __shared__ int ev_bf16, ev_bool, cnt;
        const int mb = bid - 5120;      // 0..15
        if (tid == 0) { ev_bf16 = 0; ev_bool = 0; cnt = 0; }
        __syncthreads();
        for (int i = tid; i < 1024; i += 256) {
            unsigned int w = mraw[i];
            if ((w & 0xFFFFu) == 0x3F80u) atomicOr(&ev_bf16, 1);
            if ((w & 0xFFFFFF00u) != 0u && w != 0x3F800000u) atomicOr(&ev_bool, 1);
        }
        __syncthreads();
        const int mode = ev_bf16 ? 2 : (ev_bool ? 1 : 0);
        const int e = mb * 256 + tid;
        bool on;
        if (mode == 2)      on = ((const ushort_t*)mraw)[e] != 0;
        else if (mode == 1) on = ((const unsigned char*)mraw)[e] != 0;
        else                on = mraw[e] != 0;
        maskf[e]    = on ? 1.0f : 0.0f;
        out_tail[e] = on ? 1.0f : 0.0f;
        if (!on) atomicAdd(&cnt, 1);
        __syncthreads();
        if (tid == 0) nmcnt[mb] = cnt;
    }
}

// ---------------------------------------------------------------------------
// Fused QKV GEMM (proven R11). q pre-scaled by QSC; K,V masked columns zeroed.
// ---------------------------------------------------------------------------
__global__ __launch_bounds__(256) void gemm_qkv_kernel(
    const ushort_t* __restrict__ Wqkv, const float* __restrict__ bq,
    const float* __restrict__ bk, const float* __restrict__ bv,
    const ushort_t* __restrict__ XT, const float* __restrict__ maskf,
    ushort_t* __restrict__ Qo, ushort_t* __restrict__ Ko,
    ushort_t* __restrict__ Vo) {
    __shared__ ushort_t As[128][32];
    __shared__ ushort_t Bs[128][32];
    __shared__ float biasS[128];

    const int b = blockIdx.z;
    const int m0 = blockIdx.y * 128;
    const int n0 = blockIdx.x * 128;
    const int tid = threadIdx.x;
    const int lane = tid & 63;
    const int w = tid >> 6;
    const int wm = (w & 1) * 64, wn = (w >> 1) * 64;
    const int la = lane & 15, lg = lane >> 4;
    const int region = m0 >> 10;  // 0=q 1=k 2=v

    const float* bsrc = region == 0 ? (bq + m0)
                      : (region == 1 ? (bk + m0 - 1024) : (bv + m0 - 2048));
    if (tid < 128) biasS[tid] = bsrc[tid];

    float csc[4];
    #pragma unroll
    for (int nt = 0; nt < 4; nt++) {
        const int t = n0 + wn + nt * 16 + la;
        csc[nt] = (region == 0) ? QSC : maskf[b * TT + t];
    }

    floatx4 zero4 = {0.f, 0.f, 0.f, 0.f};
    floatx4 acc[4][4];
    #pragma unroll
    for (int mt = 0; mt < 4; mt++)
        #pragma unroll
        for (int nt = 0; nt < 4; nt++) acc[mt][nt] = zero4;

    const ushort_t* Abase = Wqkv + (size_t)m0 * CC;
    const ushort_t* Bbase = XT + ((size_t)b * TT + n0) * CC;
    const int rl = lane >> 2;
    const int cl = (lane & 3) * 8;

    for (int k0 = 0; k0 < CC; k0 += 32) {
        #pragma unroll
        for (int c = 0; c < 2; c++) {
            int row = w * 32 + c * 16;
            load_lds16(Abase + (size_t)(row + rl) * CC + k0 + cl, &As[row][0]);
            load_lds16(Bbase + (size_t)(row + rl) * CC + k0 + cl, &Bs[row][0]);
        }
        __syncthreads();
        short8 af[4], bf[4];
        #pragma unroll
        for (int mt = 0; mt < 4; mt++)
            af[mt] = *(const short8*)&As[wm + mt * 16 + la][lg * 8];
        #pragma unroll
        for (int nt = 0; nt < 4; nt++)
            bf[nt] = *(const short8*)&Bs[wn + nt * 16 + la][lg * 8];
        #pragma unroll
        for (int mt = 0; mt < 4; mt++)
            #pragma unroll
            for (int nt = 0; nt < 4; nt++)
                acc[mt][nt] = MFMA(af[mt], bf[nt], acc[mt][nt]);
        __syncthreads();
    }

    #pragma unroll
    for (int mt = 0; mt < 4; mt++) {
        const int lm = wm + mt * 16 + lg * 4;
        const int gm = m0 + lm;
        #pragma unroll
        for (int nt = 0; nt < 4; nt++) {
            const int t = n0 + wn + nt * 16 + la;
            const float sc = csc[nt];
            float v0 = (acc[mt][nt][0] + biasS[lm + 0]) * sc;
            float v1 = (acc[mt][nt][1] + biasS[lm + 1]) * sc;
            float v2 = (acc[mt][nt][2] + biasS[lm + 2]) * sc;
            float v3 = (acc[mt][nt][3] + biasS[lm + 3]) * sc;
            if (region < 2) {
                int mq = gm & 1023;
                int hh = mq >> 6, db = mq & 63;
                ushort_t* dst = (region == 0 ? Qo : Ko)
                              + (((size_t)b * HH + hh) * TT + t) * DD + db;
                uint2 pk;
                pk.x = packtrunc(v0, v1);
                pk.y = packtrunc(v2, v3);
                *(uint2*)dst = pk;
            } else {
                int c = gm & 1023;
                Vo[((size_t)b * CC + c + 0) * TT + t] = f2bf_t(v0);
                Vo[((size_t)b * CC + c + 1) * TT + t] = f2bf_t(v1);
                Vo[((size_t)b * CC + c + 2) * TT + t] = f2bf_t(v2);
                Vo[((size_t)b * CC + c + 3) * TT + t] = f2bf_t(v3);
            }
        }
    }
}

// ---------------------------------------------------------------------------
// Flash attention v10: de-serialized tile loop.
//   - K/V staging via global_load_lds (no reg round-trip, no ds_writes, no
//     vmcnt(0)-before-store coupling). LDS is linear [64][64]; bank conflicts
//     avoided by XOR swizzle (col ^ ((row&7)<<4)) applied to the GLOBAL
//     source address at stage time and to precomputed ds_read addresses
//     (both-sides swizzle; glds dest stays linear).
//   - v_permlane32_swap replaces the __shfl_xor half-wave exchange: VALU-pipe
//     instead of a serial ds_bpermute round-trip in the PV dependency chain.
//   - s_setprio(1) around MFMA clusters (T5).
// ---------------------------------------------------------------------------
__global__ __launch_bounds__(256, 4) void attn_kernel(
    const ushort_t* __restrict__ Qg, const ushort_t* __restrict__ Kg,
    const ushort_t* __restrict__ Vg, const int* __restrict__ nmcnt,
    ushort_t* __restrict__ Opart, float* __restrict__ lbuf) {
    // bytes [0,16384): K bufs (p*8192); [16384,32768): V bufs (16384+p*8192)
    __shared__ __align__(16) char ldsbuf[32768];

    const int sp = blockIdx.z & 1, b = blockIdx.z >> 1;
    const int hh = blockIdx.y, t0 = blockIdx.x * 128;
    const int j0base = sp * (TT / 2);
    const int tid  = threadIdx.x;
    const int lane = tid & 63;
    const int w    = tid >> 6;
    const int ln31 = lane & 31;
    const int h    = lane >> 5;
    const size_t qkbase = ((size_t)b * HH + hh) * TT * DD;
    const size_t vbase  = ((size_t)b * CC + hh * DD) * TT;

    const int tq = t0 + w * 32 + ln31;
    short8 qreg[4];
    {
        const ushort_t* qp = Qg + qkbase + (size_t)tq * DD + h * 8;
        #pragma unroll
        for (int kc = 0; kc < 4; kc++)
            qreg[kc] = *(const short8*)(qp + kc * 16);
    }

    // ---- staging geometry ----
    // glds instruction (w,q) covers LDS rows 8*(2w+q)..+7 (1KB, lane i -> +i*16).
    // Stored content is XOR-swizzled: LDS[r][cb] = G[r][cb ^ ((r&7)<<4)],
    // achieved by pre-swizzling the per-lane global source: row = i>>3,
    // src byte-in-row = ((i&7) ^ (i>>3)) << 4.
    const int i3   = lane >> 3;                       // 0..7  (row within 8)
    const int swzb = ((lane & 7) ^ i3) << 4;          // swizzled byte-in-row
    const char* ks0 = (const char*)(Kg + qkbase + (size_t)(j0base + 16 * w + i3) * DD) + swzb;
    const char* vs0 = (const char*)(Vg + vbase + (size_t)(16 * w + i3) * TT + j0base) + swzb;
    char* kd = ldsbuf + 2 * w * 1024;                 // wave-uniform dests
    char* vd = ldsbuf + 16384 + 2 * w * 1024;

    // ---- swizzled read addresses (4 VGPRs; mt/dt fold into +4096 imm,
    //      V into +16384 imm, buffer into +p*8192 imm) ----
    int ka[4];
    {
        const int kxor = (ln31 & 7) << 4;
        #pragma unroll
        for (int kc = 0; kc < 4; kc++)
            ka[kc] = ln31 * 128 + ((kc * 32 + h * 16) ^ kxor);
    }

    floatx16 zero16 = {0.f,0.f,0.f,0.f,0.f,0.f,0.f,0.f,
                       0.f,0.f,0.f,0.f,0.f,0.f,0.f,0.f};
    floatx16 oacc[2];
    oacc[0] = zero16; oacc[1] = zero16;
    floatx16 lacc = zero16;              // every reg = sum_k p[k][q]
    short8 ones8;
    #pragma unroll
    for (int i = 0; i < 8; i++) ones8[i] = (short)0x3F80;   // bf16 1.0

    // prologue: stage tile 0 into buf 0
    load_lds16(ks0,          kd);
    load_lds16(ks0 + 1024,   kd + 1024);     // q=1: +8 K rows = +1KB contiguous
    load_lds16(vs0,          vd);
    load_lds16(vs0 + 32768,  vd + 1024);     // q=1: +8 V rows = +8*TT*2 bytes
    ks0 += 8192; vs0 += 128;
    __syncthreads();   // drains vmcnt(0): tile 0 staged

    #pragma unroll 2
    for (int kt = 0; kt < 16; kt++) {
        const int pp = (kt & 1) * 8192;          // current buffer byte offset
        const int pn = 8192 - pp;                // next buffer byte offset
        // issue stage of tile kt+1 first: in flight across this tile's compute
        if (kt < 15) {
            load_lds16(ks0,         kd + pn);
            load_lds16(ks0 + 1024,  kd + pn + 1024);
            load_lds16(vs0,         vd + pn);
            load_lds16(vs0 + 32768, vd + pn + 1024);
            ks0 += 8192; vs0 += 128;
        }

        // ---- S^T = K · Q^T ----
        floatx16 sacc[2];
        sacc[0] = zero16; sacc[1] = zero16;
        __builtin_amdgcn_s_setprio(1);
        #pragma unroll
        for (int kc = 0; kc < 4; kc++) {
            short8 kf0 = *(const short8*)(ldsbuf + ka[kc] + pp);
            short8 kf1 = *(const short8*)(ldsbuf + ka[kc] + pp + 4096);
            sacc[0] = MFMA32(kf0, qreg[kc], sacc[0]);
            sacc[1] = MFMA32(kf1, qreg[kc], sacc[1]);
        }
        __builtin_amdgcn_s_setprio(0);

        // ---- bf16-domain Schraudolph: p_bf16 = low16(fma(s,128,PMAGIC)) ----
        unsigned int pd[16];
        #pragma unroll
        for (int mt = 0; mt < 2; mt++)
            #pragma unroll
            for (int g = 0; g < 4; g++) {
                pd[mt * 8 + g * 2 + 0] =
                    pack2bf_exp(sacc[mt][g * 4 + 0], sacc[mt][g * 4 + 1]);
                pd[mt * 8 + g * 2 + 1] =
                    pack2bf_exp(sacc[mt][g * 4 + 2], sacc[mt][g * 4 + 3]);
            }

        // ---- PV: B-frag via permlane32_swap; l-sum via ones-MFMA ----
        __builtin_amdgcn_s_setprio(1);
        #pragma unroll
        for (int kc = 0; kc < 4; kc++) {
            const int base = (kc >> 1) * 8 + (kc & 1) * 4;
            uint2v r02 = __builtin_amdgcn_permlane32_swap(
                pd[base + 0], pd[base + 2], false, false);
            uint2v r13 = __builtin_amdgcn_permlane32_swap(
                pd[base + 1], pd[base + 3], false, false);
            int4 fi;
            fi.x = (int)r02[0];
            fi.y = (int)r13[0];
            fi.z = (int)r02[1];
            fi.w = (int)r13[1];
            short8 pf = *(short8*)&fi;
            lacc = MFMA32(ones8, pf, lacc);   // all rows = sum over k (both halves)
            short8 vf0 = *(const short8*)(ldsbuf + ka[kc] + pp + 16384);
            short8 vf1 = *(const short8*)(ldsbuf + ka[kc] + pp + 16384 + 4096);
            oacc[0] = MFMA32(vf0, pf, oacc[0]);
            oacc[1] = MFMA32(vf1, pf, oacc[1]);
        }
        __builtin_amdgcn_s_setprio(0);

        // barrier drains this wave's glds (vmcnt(0)) -> next buffer ready,
        // and guarantees all waves done reading buf pp before it's restaged.
        if (kt < 15) __syncthreads();
    }

    // lacc[0] holds the full split-sum over all 1024 keys. Remove masked
    // keys' exact bf16(approx 2^0) = 0.97265625 contributions.
    float lsum = lacc[0];
    {
        const int r4 = (b * 2 + sp) * 4;
        int nm = nmcnt[r4] + nmcnt[r4 + 1] + nmcnt[r4 + 2] + nmcnt[r4 + 3];
        lsum -= (float)nm * PZERO_BF;
    }

    // ---- epilogue: Opart = O_s/l_s (bf16 RNE — O-path stays unbiased) ----
    const float inv = lsum > 0.0f ? 1.0f / lsum : 0.0f;
    ushort_t* OP = Opart + (size_t)sp * ((size_t)BB * TT * CC)
                 + ((size_t)b * TT + tq) * CC + hh * 64;
    #pragma unroll
    for (int mt = 0; mt < 2; mt++)
        #pragma unroll
        for (int g = 0; g < 4; g++) {
            int db = mt * 32 + g * 8 + h * 4;
            ushort4 pk;
            pk.x = f2bf(oacc[mt][g * 4 + 0] * inv);
            pk.y = f2bf(oacc[mt][g * 4 + 1] * inv);
            pk.z = f2bf(oacc[mt][g * 4 + 2] * inv);
            pk.w = f2bf(oacc[mt][g * 4 + 3] * inv);
            *(ushort4*)&OP[db] = pk;
        }
    if (h == 0)
        lbuf[(((size_t)sp * BB + b) * HH + hh) * TT + tq] = lsum;
}

// ---------------------------------------------------------------------------
// Combine splits: OT = w0*P0 + w1*P1, w_s = l_s/(l0+l1).
// ---------------------------------------------------------------------------
__global__ __launch_bounds__(256) void combine_kernel(
    const ushort_t* __restrict__ Opart, const float* __restrict__ lbuf,
    ushort_t* __restrict__ OT) {
    const size_t idx = ((size_t)blockIdx.x * 256 + threadIdx.x) * 8;
    const int c0 = (int)(idx & (CC - 1));
    const int t  = (int)((idx >> 10) & (TT - 1));
    const int b  = (int)(idx >> 21);
    const int hh = c0 >> 6;
    const float l0 = lbuf[(((size_t)0 * BB + b) * HH + hh) * TT + t];
    const float l1 = lbuf[(((size_t)1 * BB + b) * HH + hh) * TT + t];
    const float sum = l0 + l1;
    const float ws = sum > 0.0f ? 1.0f / sum : 0.0f;
    const float w0 = l0 * ws, w1 = l1 * ws;
    const ushort_t* P0 = Opart + idx;
    const ushort_t* P1 = Opart + (size_t)BB * TT * CC + idx;
    ushort4 a0 = *(const ushort4*)(P0);
    ushort4 a1 = *(const ushort4*)(P0 + 4);
    ushort4 b0 = *(const ushort4*)(P1);
    ushort4 b1 = *(const ushort4*)(P1 + 4);
    ushort4 o0, o1;
    o0.x = f2bf(w0 * bf2f(a0.x) + w1 * bf2f(b0.x));
    o0.y = f2bf(w0 * bf2f(a0.y) + w1 * bf2f(b0.y));
    o0.z = f2bf(w0 * bf2f(a0.z) + w1 * bf2f(b0.z));
    o0.w = f2bf(w0 * bf2f(a0.w) + w1 * bf2f(b0.w));
    o1.x = f2bf(w0 * bf2f(a1.x) + w1 * bf2f(b1.x));
    o1.y = f2bf(w0 * bf2f(a1.y) + w1 * bf2f(b1.y));
    o1.z = f2bf(w0 * bf2f(a1.z) + w1 * bf2f(b1.z));
    o1.w = f2bf(w0 * bf2f(a1.w) + w1 * bf2f(b1.w));
    *(ushort4*)&OT[idx]     = o0;
    *(ushort4*)&OT[idx + 4] = o1;
}

// ---------------------------------------------------------------------------
// Output GEMM, single-pass bf16 (proven R7/R8).
// ---------------------------------------------------------------------------
__global__ __launch_bounds__(256) void gemm_out_kernel(
    const ushort_t* __restrict__ WP, const ushort_t* __restrict__ OT,
    const float* __restrict__ bp, const float* __restrict__ maskf,
    float* __restrict__ out) {
    __shared__ ushort_t As[64][32];
    __shared__ ushort_t Bs[128][32];
    __shared__ float biasS[64];

    const int b = blockIdx.z;
    const int m0 = blockIdx.y * 64;
    const int n0 = blockIdx.x * 128;
    const int tid = threadIdx.x;
    const int lane = tid & 63;
    const int w = tid >> 6;
    const int wm = (w & 1) * 32, wn = (w >> 1) * 64;
    const int la = lane & 15, lg = lane >> 4;

    if (tid < 64) biasS[tid] = bp[m0 + tid];

    floatx4 zero4 = {0.f, 0.f, 0.f, 0.f};
    floatx4 acc[2][4];
    #pragma unroll
    for (int mt = 0; mt < 2; mt++)
        #pragma unroll
        for (int nt = 0; nt < 4; nt++) acc[mt][nt] = zero4;

    const int rl = lane >> 2;
    const int cl = (lane & 3) * 8;
    const ushort_t* Bbase = OT + ((size_t)b * TT + n0) * CC;

    for (int k0 = 0; k0 < CC; k0 += 32) {
        {
            int row = w * 16;
            load_lds16(WP + (size_t)(m0 + row + rl) * CC + k0 + cl, &As[row][0]);
        }
        #pragma unroll
        for (int c = 0; c < 2; c++) {
            int row = w * 32 + c * 16;
            load_lds16(Bbase + (size_t)(row + rl) * CC + k0 + cl, &Bs[row][0]);
        }
        __syncthreads();
        short8 af[2], bf[4];
        #pragma unroll
        for (int mt = 0; mt < 2; mt++)
            af[mt] = *(const short8*)&As[wm + mt * 16 + la][lg * 8];
        #pragma unroll
        for (int nt = 0; nt < 4; nt++)
            bf[nt] = *(const short8*)&Bs[wn + nt * 16 + la][lg * 8];
        #pragma unroll
        for (int mt = 0; mt < 2; mt++)
            #pragma unroll
            for (int nt = 0; nt < 4; nt++)
                acc[mt][nt] = MFMA(af[mt], bf[nt], acc[mt][nt]);
        __syncthreads();
    }

    #pragma unroll
    for (int mt = 0; mt < 2; mt++) {
        const int lm = wm + mt * 16 + lg * 4;
        #pragma unroll
        for (int nt = 0; nt < 4; nt++) {
            const int t = n0 + wn + nt * 16 + la;
            const float mk = maskf[b * TT + t];
            #pragma unroll
            for (int r = 0; r < 4; r++)
                out[((size_t)b * CC + m0 + lm + r) * TT + t] =
                    (acc[mt][nt][r] + biasS[lm + r]) * mk;
        }
    }
}

// ---------------------------------------------------------------------------
extern "C" void kernel_launch(void* const* d_in, const int* in_sizes, int n_in,
                              void* d_out, int out_size, void* d_ws,
                              size_t ws_size, hipStream_t stream) {
    const float* x    = (const float*)d_in[0];
    const void*  mask = d_in[1];
    const float* Wq   = (const float*)d_in[2];
    const float* bq   = (const float*)d_in[3];
    const float* Wk   = (const float*)d_in[4];
    const float* bk   = (const float*)d_in[5];
    const float* Wv   = (const float*)d_in[6];
    const float* bv   = (const float*)d_in[7];
    const float* Wp   = (const float*)d_in[8];
    const float* bp   = (const float*)d_in[9];

    float* out  = (float*)d_out;
    float* wsf  = (float*)d_ws;
    int* nmcnt  = (int*)d_ws + 16;     // 16 per-block masked counts
    float* maskf = wsf + 1024;
    char* wsb = (char*)d_ws;
    ushort_t* XT    = (ushort_t*)(wsb + XT_OFF);   // also final OT
    ushort_t* WQKV  = (ushort_t*)(wsb + WQKV_OFF);
    ushort_t* WPb   = (ushort_t*)(wsb + WP_OFF);
    ushort_t* Qb    = (ushort_t*)(wsb + Q_OFF);
    ushort_t* Kb    = (ushort_t*)(wsb + K_OFF);
    ushort_t* Vb    = (ushort_t*)(wsb + V_OFF);
    ushort_t* Opart = (ushort_t*)(wsb + OP_OFF);
    float*    lbuf  = (float*)(wsb + ML_OFF);

    prep_kernel<<<5136, 256, 0, stream>>>(x, Wq, Wk, Wv, Wp,
                                          (const unsigned int*)mask, XT, WQKV,
                                          WPb, maskf, nmcnt,
                                          out + (size_t)BB * CC * TT);

    gemm_qkv_kernel<<<dim3(TT / 128, 3 * CC / 128, BB), 256, 0, stream>>>(
        WQKV, bq, bk, bv, XT, maskf, Qb, Kb, Vb);

    attn_kernel<<<dim3(TT / 128, HH, BB * 2), 256, 0, stream>>>(
        Qb, Kb, Vb, nmcnt, Opart, lbuf);

    combine_kernel<<<2048, 256, 0, stream>>>(Opart, lbuf, XT);

    gemm_out_kernel<<<dim3(TT / 128, CC / 64, BB), 256, 0, stream>>>(
        WPb, XT, bp, maskf, out);
}